// Round 4
// baseline (301.508 us; speedup 1.0000x reference)
//
#include <hip/hip_runtime.h>
#include <math.h>

// SSIM-with-logits fused kernel for MI355X (gfx950). Round 8.
// R7 post-mortem: VGPR=100 -> occupancy 22%, dur 178us = exactly 2x R4's
// 90us (two rounds of 2 blocks/CU). Empirical residency model fitting ALL
// rounds: waves/SIMD = floor(256 / arch VGPR). Cliffs at 85 (3/SIMD) and
// 64 (4/SIMD). R4/R5/R7 at VGPR 100-128 were all pinned to 2/SIMD.
// R8 attacks the register count to get under the 85 cliff:
//  - sigma-sum trick: SSIM needs only sigma1^2+sigma2^2, so carry
//    vSX=(F(aa)+F(bb), F(ab)) as ONE f2 ring -> ring 56->44 regs, and
//    vertical scatter 28->22 fma/row. FP reassoc is sub-ulp.
//  - no deep prefetch; thrifty addressing. Target ~70-80 VGPR total.
//  - TILE_W=128, 128-thread (2-wave) blocks, TILE_H=64: 2048 blocks,
//    12.3 KB LDS. At 3 waves/SIMD -> 6 independent small blocks/CU;
//    stage/barrier phases of one block hide under VALU of the others
//    (R7's 4-wave convoy at 2 blocks/CU dissolves).
//  - __launch_bounds__(128) only (no waves-per-eu arg).

typedef __attribute__((ext_vector_type(2))) float f2;

#define H_IMG 1024
#define W_IMG 1024
#define N_IMG 16
#define TILE_W 128
#define TILE_H 64
#define PADR 5
#define LDS_S2 140  // f2 cells per staged row (>= 138)

// Normalized 1D Gaussian, WS=11, sigma=1.5 (absmax 0.0 in R1-R7)
constexpr float GW[11] = {
    0.00102838f, 0.00759877f, 0.03600077f, 0.10936069f, 0.21300553f,
    0.26601172f,
    0.21300553f, 0.10936069f, 0.03600077f, 0.00759877f, 0.00102838f};

__device__ __forceinline__ int reflect_i(int i, int n) {
    i = (i < 0) ? -i : i;
    i = (i >= n) ? (2 * n - 2 - i) : i;
    return i;
}

__device__ __forceinline__ float fast_sigmoid(float x) {
    return __builtin_amdgcn_rcpf(1.0f + __expf(-x));
}

// mu = (mu1, mu2); sx = (F(a^2)+F(b^2), F(ab))
__device__ __forceinline__ void ssim_emit(
    f2 mu, f2 sx, float& loss_sum)
{
    const float mu1 = mu.x, mu2 = mu.y;
    const float mu1s = mu1 * mu1;
    const float mu2s = mu2 * mu2;
    const float mu12 = mu1 * mu2;
    const float ssum = sx.x - mu1s - mu2s;   // sigma1^2 + sigma2^2
    const float s12  = sx.y - mu12;
    const float C1 = 1e-4f, C2 = 9e-4f;
    const float num = (2.0f * mu12 + C1) * (2.0f * s12 + C2);
    const float den = (mu1s + mu2s + C1) * (ssum + C2);
    float l = 1.0f - num * __builtin_amdgcn_rcpf(den);
    l = fminf(fmaxf(l, 0.0f), 1.0f) * 0.5f;
    loss_sum += l;
}

// Stage NR rows of the group at base gb: global -> (sigmoid) -> LDS.
template<int NR>
__device__ __forceinline__ void stage_group(
    const float* __restrict__ A, const float* __restrict__ B,
    int y_start, int gb, int c0, int c1, int tid,
    f2 (*__restrict__ buf)[LDS_S2])
{
#pragma unroll 2
    for (int r = 0; r < NR; ++r) {
        const int yy = reflect_i(y_start + gb + r, H_IMG);
        const size_t ro = (size_t)yy << 10;   // *W_IMG (1024)
        const float a0 = A[ro + c0];
        const float b0 = B[ro + c0];
        float a1 = 0.0f, b1 = 0.0f;
        const bool halo = (tid < 2 * PADR);
        if (halo) {
            a1 = A[ro + c1];
            b1 = B[ro + c1];
        }
        buf[r][tid] = (f2){fast_sigmoid(a0), b0};
        if (halo)
            buf[r][TILE_W + tid] = (f2){fast_sigmoid(a1), b1};
    }
}

// Process NR staged rows. Group base == 0 mod 11 so slot indices fold to
// compile-time constants (validated R2-R7, absmax 0.0). GUARD: first group
// (edge); invalid taps skipped, only r==10 completes an output.
template<int NR, bool GUARD>
__device__ __forceinline__ void process_group(
    const f2 (*__restrict__ buf)[LDS_S2], int tid,
    f2 (&vAB)[11], f2 (&vSX)[11], float& loss_sum)
{
#pragma unroll
    for (int r = 0; r < NR; ++r) {
        // ---- horizontal 11-tap, packed (a,b)/(aa,bb) + scalar ab ----
        f2 hAB = (f2)(0.0f), hSQ = (f2)(0.0f);
        float hab = 0.0f;
#pragma unroll
        for (int k = 0; k < 11; ++k) {
            const f2 v   = buf[r][tid + k];
            const f2 wa2 = ((f2)(GW[k])) * v;         // (GW*a, GW*b)
            hAB += wa2;
            hSQ  = __builtin_elementwise_fma(wa2, v, hSQ);
            hab  = fmaf(wa2.x, v.y, hab);
        }
        // collapse (aa,bb) -> aa+bb; pair with ab
        const f2 hSX = (f2){hSQ.x + hSQ.y, hab};
        // ---- vertical scatter into mod-11 slots: 22 pk_fma ----
#pragma unroll
        for (int j = 0; j < 11; ++j) {
            if (!(GUARD && j > r)) {
                const int s = (r - j + 22) % 11;
                const f2 w2 = (f2)(GW[j]);
                vAB[s] = __builtin_elementwise_fma(w2, hAB, vAB[s]);
                vSX[s] = __builtin_elementwise_fma(w2, hSX, vSX[s]);
            }
        }
        // ---- completion: slot (r+1)%11 finished an output row ----
        if (!GUARD || r == 10) {
            const int s = (r + 1) % 11;
            ssim_emit(vAB[s], vSX[s], loss_sum);
            vAB[s] = (f2)(0.0f); vSX[s] = (f2)(0.0f);
        }
    }
}

__global__ __launch_bounds__(128) void ssim_main(
    const float* __restrict__ inp, const float* __restrict__ tgt,
    float* __restrict__ out)
{
    __shared__ f2 buf[11][LDS_S2];   // single buffer, ~12.3 KB
    __shared__ float red[2];

    const int tid = threadIdx.x;
    const int blk = blockIdx.x;
    const int b   = blk >> 7;           // image 0..15 (128 blocks/image)
    const int rem = blk & 127;
    const int cx  = rem & 7;            // column tile 0..7
    const int ry  = rem >> 3;           // row band 0..15
    const int x0  = cx * TILE_W;
    const int y0  = ry * TILE_H;

    const float* __restrict__ A = inp + (size_t)b * (H_IMG * (size_t)W_IMG);
    const float* __restrict__ B = tgt + (size_t)b * (H_IMG * (size_t)W_IMG);

    const int c0 = reflect_i(x0 - PADR + tid, W_IMG);
    const int c1 = (tid < 2 * PADR) ? reflect_i(x0 + TILE_W - PADR + tid, W_IMG) : 0;

    f2 vAB[11], vSX[11];
#pragma unroll
    for (int j = 0; j < 11; ++j) {
        vAB[j] = (f2)(0.0f); vSX[j] = (f2)(0.0f);
    }
    float loss_sum = 0.0f;

    const int y_start = y0 - PADR;  // 74 input rows: 6 groups of 11 + 8

    // group 0 (edge-guarded)
    stage_group<11>(A, B, y_start, 0, c0, c1, tid, buf);
    __syncthreads();
    process_group<11, true>(buf, tid, vAB, vSX, loss_sum);

    // groups 1..5: WAR barrier, stage, RAW barrier, process.
    // 2-wave blocks: barrier rendezvous is cheap; stage latency of this
    // block hides under VALU of the ~5 other resident blocks on the CU.
#pragma unroll 1
    for (int g = 1; g <= 5; ++g) {
        __syncthreads();                 // all waves done reading buf
        stage_group<11>(A, B, y_start, g * 11, c0, c1, tid, buf);
        __syncthreads();                 // writes visible
        process_group<11, false>(buf, tid, vAB, vSX, loss_sum);
    }

    // tail: group 6, rows 66..73 (66 % 11 == 0)
    __syncthreads();
    stage_group<8>(A, B, y_start, 66, c0, c1, tid, buf);
    __syncthreads();
    process_group<8, false>(buf, tid, vAB, vSX, loss_sum);

    // ---- reduction: wave64 shuffle -> LDS across 2 waves -> atomicAdd ----
#pragma unroll
    for (int off = 32; off > 0; off >>= 1)
        loss_sum += __shfl_down(loss_sum, off, 64);
    const int wave = tid >> 6;
    if ((tid & 63) == 0) red[wave] = loss_sum;
    __syncthreads();
    if (tid == 0) {
        const float s = red[0] + red[1];
        atomicAdd(out, s * (1.0f / ((float)N_IMG * H_IMG * W_IMG)));
    }
}

extern "C" void kernel_launch(void* const* d_in, const int* in_sizes, int n_in,
                              void* d_out, int out_size, void* d_ws, size_t ws_size,
                              hipStream_t stream) {
    const float* inp = (const float*)d_in[0];
    const float* tgt = (const float*)d_in[1];
    float* out = (float*)d_out;

    // d_out is poisoned 0xAA before every launch; zero it for the atomic sum.
    hipMemsetAsync(out, 0, sizeof(float), stream);

    const int grid = N_IMG * (W_IMG / TILE_W) * (H_IMG / TILE_H);  // 2048
    ssim_main<<<grid, 128, 0, stream>>>(inp, tgt, out);
}

// Round 5
// 183.151 us; speedup vs baseline: 1.6462x; 1.6462x over previous
//
#include <hip/hip_runtime.h>
#include <math.h>

// SSIM-with-logits fused kernel for MI355X (gfx950). Round 9.
// R8 post-mortem: VGPR=72, LDS=12.8KB, no spill -- occupancy STILL ~23%,
// dur 206us. The VGPR->occupancy model is falsified; occupancy never
// responds to resources. Best config remains R4 (90us, VALU 57%): deep
// prefetch + double-buffer + 1 barrier/group. Its 43% idle is correlated
// stalls: barriers synchronize all waves, so they hit the same ds_read /
// vmcnt waits simultaneously and cannot cover each other.
// R9: R4's exact pipeline made PER-WAVE, zero barriers.
//  - each wave owns a private 64-col (+10 halo) tile and private
//    double-buffered 11-row LDS group buffers (13.4KB/wave, 53.5KB/block)
//  - LDS producer->consumer is within-wave: DS ops are in-order per wave
//    (lgkmcnt FIFO), so NO __syncthreads anywhere in the pipeline
//  - waves run phase-staggered -> stalls decorrelate; wave1 issues FMAs
//    while wave0 waits on its ds_read burst
//  - R4's proven 138-row / 12x11+6 group schedule + deep register
//    prefetch verbatim; R8's sigma-sum ring (proven exact) cuts the
//    vertical pass 33->22 fma/row and the ring 56->44 regs
//  - __launch_bounds__(256,2): the only spill-free bound (R3/R5/R6)

typedef __attribute__((ext_vector_type(2))) float f2;

#define H_IMG 1024
#define W_IMG 1024
#define N_IMG 16
#define WAVE_W 64        // output columns per wave
#define TILE_H 128       // output rows per wave
#define PADR 5
#define LDS_S2 76        // f2 cells per staged row (64 + 10 halo + pad)

// Normalized 1D Gaussian, WS=11, sigma=1.5 (absmax 0.0 in R1-R8)
constexpr float GW[11] = {
    0.00102838f, 0.00759877f, 0.03600077f, 0.10936069f, 0.21300553f,
    0.26601172f,
    0.21300553f, 0.10936069f, 0.03600077f, 0.00759877f, 0.00102838f};

__device__ __forceinline__ int reflect_i(int i, int n) {
    i = (i < 0) ? -i : i;
    i = (i >= n) ? (2 * n - 2 - i) : i;
    return i;
}

__device__ __forceinline__ float fast_sigmoid(float x) {
    return __builtin_amdgcn_rcpf(1.0f + __expf(-x));
}

// mu = (mu1, mu2); sx = (F(a^2)+F(b^2), F(ab))  [sigma-sum trick, R8-proven]
__device__ __forceinline__ void ssim_emit(
    f2 mu, f2 sx, float& loss_sum)
{
    const float mu1 = mu.x, mu2 = mu.y;
    const float mu1s = mu1 * mu1;
    const float mu2s = mu2 * mu2;
    const float mu12 = mu1 * mu2;
    const float ssum = sx.x - mu1s - mu2s;   // sigma1^2 + sigma2^2
    const float s12  = sx.y - mu12;
    const float C1 = 1e-4f, C2 = 9e-4f;
    const float num = (2.0f * mu12 + C1) * (2.0f * s12 + C2);
    const float den = (mu1s + mu2s + C1) * (ssum + C2);
    float l = 1.0f - num * __builtin_amdgcn_rcpf(den);
    l = fminf(fmaxf(l, 0.0f), 1.0f) * 0.5f;
    loss_sum += l;
}

// Issue global loads for NR rows of group at base gb into prefetch regs.
template<int NR>
__device__ __forceinline__ void load_group(
    const float* __restrict__ A, const float* __restrict__ B,
    int y_start, int gb, int c0, int c1, int lane,
    float (&pa)[11], float (&pb)[11], float (&pa2)[11], float (&pb2)[11])
{
#pragma unroll
    for (int r = 0; r < NR; ++r) {
        const int yy = reflect_i(y_start + gb + r, H_IMG);
        const size_t ro = (size_t)yy << 10;   // *W_IMG
        pa[r] = A[ro + c0];
        pb[r] = B[ro + c0];
        if (lane < 2 * PADR) {
            pa2[r] = A[ro + c1];
            pb2[r] = B[ro + c1];
        }
    }
}

// Sigmoid + write NR prefetched rows into this wave's LDS buffer.
template<int NR>
__device__ __forceinline__ void write_group(
    f2 (*__restrict__ buf)[LDS_S2], int lane,
    const float (&pa)[11], const float (&pb)[11],
    const float (&pa2)[11], const float (&pb2)[11])
{
#pragma unroll
    for (int r = 0; r < NR; ++r) {
        buf[r][lane] = (f2){fast_sigmoid(pa[r]), pb[r]};
        if (lane < 2 * PADR)
            buf[r][WAVE_W + lane] = (f2){fast_sigmoid(pa2[r]), pb2[r]};
    }
}

// Process NR staged rows from this wave's buffer. Group base == 0 mod 11
// so mod-11 slot indices fold to compile-time constants (validated R2-R8).
// GUARD: first group (edge); invalid taps skipped, only r==10 completes.
// No barrier needed: DS reads follow this wave's own DS writes in order.
template<int NR, bool GUARD>
__device__ __forceinline__ void process_group(
    const f2 (*__restrict__ buf)[LDS_S2], int lane,
    f2 (&vAB)[11], f2 (&vSX)[11], float& loss_sum)
{
#pragma unroll
    for (int r = 0; r < NR; ++r) {
        // ---- horizontal 11-tap, packed (a,b)/(aa,bb) + scalar ab ----
        f2 hAB = (f2)(0.0f), hSQ = (f2)(0.0f);
        float hab = 0.0f;
#pragma unroll
        for (int k = 0; k < 11; ++k) {
            const f2 v   = buf[r][lane + k];
            const f2 wa2 = ((f2)(GW[k])) * v;         // (GW*a, GW*b)
            hAB += wa2;
            hSQ  = __builtin_elementwise_fma(wa2, v, hSQ);
            hab  = fmaf(wa2.x, v.y, hab);
        }
        // collapse (aa,bb) -> aa+bb; pair with ab
        const f2 hSX = (f2){hSQ.x + hSQ.y, hab};
        // ---- vertical scatter into mod-11 slots: 22 pk_fma ----
#pragma unroll
        for (int j = 0; j < 11; ++j) {
            if (!(GUARD && j > r)) {
                const int s = (r - j + 22) % 11;
                const f2 w2 = (f2)(GW[j]);
                vAB[s] = __builtin_elementwise_fma(w2, hAB, vAB[s]);
                vSX[s] = __builtin_elementwise_fma(w2, hSX, vSX[s]);
            }
        }
        // ---- completion: slot (r+1)%11 finished an output row ----
        if (!GUARD || r == 10) {
            const int s = (r + 1) % 11;
            ssim_emit(vAB[s], vSX[s], loss_sum);
            vAB[s] = (f2)(0.0f); vSX[s] = (f2)(0.0f);
        }
    }
}

__global__ __launch_bounds__(256, 2) void ssim_main(
    const float* __restrict__ inp, const float* __restrict__ tgt,
    float* __restrict__ out)
{
    // Per-wave private double-buffered group storage: 4 waves x 2 bufs.
    __shared__ f2 lds[4][2][11][LDS_S2];   // 53.5 KB
    __shared__ float red[4];

    const int tid  = threadIdx.x;
    const int lane = tid & 63;
    const int w    = tid >> 6;          // wave 0..3
    const int blk  = blockIdx.x;
    // 2048 wave-tiles: img(16) x colstrip(16) x band(8); 4 strips/block
    const int b    = blk >> 5;          // image 0..15
    const int rem  = blk & 31;
    const int ry   = rem >> 2;          // row band 0..7
    const int cs   = (rem & 3) * 4 + w; // column strip 0..15
    const int x0   = cs * WAVE_W;
    const int y0   = ry * TILE_H;

    const float* __restrict__ A = inp + (size_t)b * (H_IMG * (size_t)W_IMG);
    const float* __restrict__ B = tgt + (size_t)b * (H_IMG * (size_t)W_IMG);

    const int c0 = reflect_i(x0 - PADR + lane, W_IMG);
    const int c1 = (lane < 2 * PADR)
                       ? reflect_i(x0 + WAVE_W - PADR + lane, W_IMG) : 0;

    f2 vAB[11], vSX[11];
#pragma unroll
    for (int j = 0; j < 11; ++j) {
        vAB[j] = (f2)(0.0f); vSX[j] = (f2)(0.0f);
    }
    float pa[11], pb[11], pa2[11], pb2[11];
    float loss_sum = 0.0f;

    const int y_start = y0 - PADR;  // 138 input rows: 12 groups of 11 + 6

    // prologue: group 0 staged, group 1 prefetched — all within-wave.
    load_group<11>(A, B, y_start, 0, c0, c1, lane, pa, pb, pa2, pb2);
    write_group<11>(lds[w][0], lane, pa, pb, pa2, pb2);
    load_group<11>(A, B, y_start, 11, c0, c1, lane, pa, pb, pa2, pb2);
    process_group<11, true>(lds[w][0], lane, vAB, vSX, loss_sum);

    // main loop: NO barriers. write(g) -> load(g+1) -> process(g).
    // DS in-order per wave makes write->read safe; the buffer parity keeps
    // process(g) reads separate from write(g+1) of the next iteration.
#pragma unroll 1
    for (int g = 1; g <= 11; ++g) {
        f2 (*cur)[LDS_S2] = lds[w][g & 1];
        write_group<11>(cur, lane, pa, pb, pa2, pb2);   // prefetched group g
        if (g <= 10)
            load_group<11>(A, B, y_start, (g + 1) * 11, c0, c1, lane,
                           pa, pb, pa2, pb2);
        else
            load_group<6>(A, B, y_start, 132, c0, c1, lane,
                          pa, pb, pa2, pb2);
        process_group<11, false>(cur, lane, vAB, vSX, loss_sum);
    }

    // tail: group 12, rows 132..137 (132 % 11 == 0)
    write_group<6>(lds[w][0], lane, pa, pb, pa2, pb2);
    process_group<6, false>(lds[w][0], lane, vAB, vSX, loss_sum);

    // ---- reduction: wave shuffle -> LDS across 4 waves -> atomicAdd ----
#pragma unroll
    for (int off = 32; off > 0; off >>= 1)
        loss_sum += __shfl_down(loss_sum, off, 64);
    if (lane == 0) red[w] = loss_sum;
    __syncthreads();   // the only barrier: final 4-wave reduction
    if (tid == 0) {
        const float s = red[0] + red[1] + red[2] + red[3];
        atomicAdd(out, s * (1.0f / ((float)N_IMG * H_IMG * W_IMG)));
    }
}

extern "C" void kernel_launch(void* const* d_in, const int* in_sizes, int n_in,
                              void* d_out, int out_size, void* d_ws, size_t ws_size,
                              hipStream_t stream) {
    const float* inp = (const float*)d_in[0];
    const float* tgt = (const float*)d_in[1];
    float* out = (float*)d_out;

    // d_out is poisoned 0xAA before every launch; zero it for the atomic sum.
    hipMemsetAsync(out, 0, sizeof(float), stream);

    const int grid = N_IMG * 4 * (H_IMG / TILE_H);  // 512 blocks x 4 waves
    ssim_main<<<grid, 256, 0, stream>>>(inp, tgt, out);
}

// Round 7
// 182.001 us; speedup vs baseline: 1.6566x; 1.0063x over previous
//
#include <hip/hip_runtime.h>
#include <math.h>

// SSIM-with-logits fused kernel for MI355X (gfx950). Round 11 (R10 fix).
// R10 failed to assemble: VOP3P packed-f32 sources must be 64-bit VGPR
// PAIRS; there is no single-VGPR broadcast via op_sel_hi. Fix: weights
// are materialized as (w,w) f2 pairs (11 pairs, loop-invariant, ~22 VGPR,
// hoisted) and all pk ops take pair operands.
// Theory unchanged from R10: R9's 53us VALU busy-time matches SCALAR
// emission of the f2 math (~121 instr/row). Forcing v_pk_{mul,add,fma}_f32
// cuts core math to ~68 instr/row. Per-element IEEE identical -> absmax 0.
//  - horizontal tap: pk_mul + pk_add + pk_fma + 1 scalar fma (was 7 scalar)
//  - vertical slot: 2x pk_fma (was 4 scalar)
// Pipe balance after: VALU ~28-34us, LDS ~25us, HBM ~21us.
// Falsification: dur unchanged => instr count not the limiter => pivot to
// ds_read latency hiding (row-ahead tap prefetch).

typedef __attribute__((ext_vector_type(2))) float f2;

#define H_IMG 1024
#define W_IMG 1024
#define N_IMG 16
#define WAVE_W 64        // output columns per wave
#define TILE_H 128       // output rows per wave
#define PADR 5
#define LDS_S2 76        // f2 cells per staged row (64 + 10 halo + pad)

// Normalized 1D Gaussian, WS=11, sigma=1.5 (absmax 0.0 in R1-R9)
constexpr float GW[11] = {
    0.00102838f, 0.00759877f, 0.03600077f, 0.10936069f, 0.21300553f,
    0.26601172f,
    0.21300553f, 0.10936069f, 0.03600077f, 0.00759877f, 0.00102838f};

// ---- VOP3P packed-f32 helpers (gfx90a+/CDNA4). All operands are VGPR
// pairs (64-bit); elementwise semantics, bit-identical to scalar IEEE.
__device__ __forceinline__ f2 pk_mul(f2 a, f2 b) {
    f2 d;
    asm("v_pk_mul_f32 %0, %1, %2" : "=v"(d) : "v"(a), "v"(b));
    return d;
}
__device__ __forceinline__ f2 pk_add(f2 a, f2 b) {
    f2 d;
    asm("v_pk_add_f32 %0, %1, %2" : "=v"(d) : "v"(a), "v"(b));
    return d;
}
__device__ __forceinline__ f2 pk_fma(f2 a, f2 b, f2 c) {
    f2 d;
    asm("v_pk_fma_f32 %0, %1, %2, %3"
        : "=v"(d) : "v"(a), "v"(b), "v"(c));
    return d;
}

__device__ __forceinline__ int reflect_i(int i, int n) {
    i = (i < 0) ? -i : i;
    i = (i >= n) ? (2 * n - 2 - i) : i;
    return i;
}

__device__ __forceinline__ float fast_sigmoid(float x) {
    return __builtin_amdgcn_rcpf(1.0f + __expf(-x));
}

// mu = (mu1, mu2); sx = (F(a^2)+F(b^2), F(ab))  [sigma-sum trick, R8-proven]
__device__ __forceinline__ void ssim_emit(
    f2 mu, f2 sx, float& loss_sum)
{
    const float mu1 = mu.x, mu2 = mu.y;
    const float mu1s = mu1 * mu1;
    const float mu2s = mu2 * mu2;
    const float mu12 = mu1 * mu2;
    const float ssum = sx.x - mu1s - mu2s;   // sigma1^2 + sigma2^2
    const float s12  = sx.y - mu12;
    const float C1 = 1e-4f, C2 = 9e-4f;
    const float num = (2.0f * mu12 + C1) * (2.0f * s12 + C2);
    const float den = (mu1s + mu2s + C1) * (ssum + C2);
    float l = 1.0f - num * __builtin_amdgcn_rcpf(den);
    l = fminf(fmaxf(l, 0.0f), 1.0f) * 0.5f;
    loss_sum += l;
}

// Issue global loads for NR rows of group at base gb into prefetch regs.
template<int NR>
__device__ __forceinline__ void load_group(
    const float* __restrict__ A, const float* __restrict__ B,
    int y_start, int gb, int c0, int c1, int lane,
    float (&pa)[11], float (&pb)[11], float (&pa2)[11], float (&pb2)[11])
{
#pragma unroll
    for (int r = 0; r < NR; ++r) {
        const int yy = reflect_i(y_start + gb + r, H_IMG);
        const size_t ro = (size_t)yy << 10;   // *W_IMG
        pa[r] = A[ro + c0];
        pb[r] = B[ro + c0];
        if (lane < 2 * PADR) {
            pa2[r] = A[ro + c1];
            pb2[r] = B[ro + c1];
        }
    }
}

// Sigmoid + write NR prefetched rows into this wave's LDS buffer.
template<int NR>
__device__ __forceinline__ void write_group(
    f2 (*__restrict__ buf)[LDS_S2], int lane,
    const float (&pa)[11], const float (&pb)[11],
    const float (&pa2)[11], const float (&pb2)[11])
{
#pragma unroll
    for (int r = 0; r < NR; ++r) {
        buf[r][lane] = (f2){fast_sigmoid(pa[r]), pb[r]};
        if (lane < 2 * PADR)
            buf[r][WAVE_W + lane] = (f2){fast_sigmoid(pa2[r]), pb2[r]};
    }
}

// Process NR staged rows from this wave's buffer. Group base == 0 mod 11
// so mod-11 slot indices fold to compile-time constants (validated R2-R9).
// GUARD: first group (edge); invalid taps skipped, only r==10 completes.
// No barrier needed: DS reads follow this wave's own DS writes in order.
template<int NR, bool GUARD>
__device__ __forceinline__ void process_group(
    const f2 (*__restrict__ buf)[LDS_S2], int lane,
    const f2 (&W2)[11],
    f2 (&vAB)[11], f2 (&vSX)[11], float& loss_sum)
{
#pragma unroll
    for (int r = 0; r < NR; ++r) {
        // ---- horizontal 11-tap: 3 VOP3P + 1 scalar per tap ----
        f2 hAB = (f2)(0.0f), hSQ = (f2)(0.0f);
        float hab = 0.0f;
#pragma unroll
        for (int k = 0; k < 11; ++k) {
            const f2 v   = buf[r][lane + k];
            const f2 wa2 = pk_mul(W2[k], v);          // (GW*a, GW*b)
            hAB = pk_add(hAB, wa2);
            hSQ = pk_fma(wa2, v, hSQ);                // (GW*aa, GW*bb)
            hab = fmaf(wa2.x, v.y, hab);              // GW*ab
        }
        // collapse (aa,bb) -> aa+bb; pair with ab
        const f2 hSX = (f2){hSQ.x + hSQ.y, hab};
        // ---- vertical scatter into mod-11 slots: 2 VOP3P per slot ----
#pragma unroll
        for (int j = 0; j < 11; ++j) {
            if (!(GUARD && j > r)) {
                const int s = (r - j + 22) % 11;
                vAB[s] = pk_fma(W2[j], hAB, vAB[s]);
                vSX[s] = pk_fma(W2[j], hSX, vSX[s]);
            }
        }
        // ---- completion: slot (r+1)%11 finished an output row ----
        if (!GUARD || r == 10) {
            const int s = (r + 1) % 11;
            ssim_emit(vAB[s], vSX[s], loss_sum);
            vAB[s] = (f2)(0.0f); vSX[s] = (f2)(0.0f);
        }
    }
}

__global__ __launch_bounds__(256, 2) void ssim_main(
    const float* __restrict__ inp, const float* __restrict__ tgt,
    float* __restrict__ out)
{
    // Per-wave private double-buffered group storage: 4 waves x 2 bufs.
    __shared__ f2 lds[4][2][11][LDS_S2];   // 53.5 KB
    __shared__ float red[4];

    const int tid  = threadIdx.x;
    const int lane = tid & 63;
    const int w    = tid >> 6;          // wave 0..3
    const int blk  = blockIdx.x;
    // 2048 wave-tiles: img(16) x colstrip(16) x band(8); 4 strips/block
    const int b    = blk >> 5;          // image 0..15
    const int rem  = blk & 31;
    const int ry   = rem >> 2;          // row band 0..7
    const int cs   = (rem & 3) * 4 + w; // column strip 0..15
    const int x0   = cs * WAVE_W;
    const int y0   = ry * TILE_H;

    const float* __restrict__ A = inp + (size_t)b * (H_IMG * (size_t)W_IMG);
    const float* __restrict__ B = tgt + (size_t)b * (H_IMG * (size_t)W_IMG);

    const int c0 = reflect_i(x0 - PADR + lane, W_IMG);
    const int c1 = (lane < 2 * PADR)
                       ? reflect_i(x0 + WAVE_W - PADR + lane, W_IMG) : 0;

    // Loop-invariant (w,w) weight pairs for VOP3P (11 pairs, hoisted).
    f2 W2[11];
#pragma unroll
    for (int j = 0; j < 11; ++j) W2[j] = (f2){GW[j], GW[j]};

    f2 vAB[11], vSX[11];
#pragma unroll
    for (int j = 0; j < 11; ++j) {
        vAB[j] = (f2)(0.0f); vSX[j] = (f2)(0.0f);
    }
    float pa[11], pb[11], pa2[11], pb2[11];
    float loss_sum = 0.0f;

    const int y_start = y0 - PADR;  // 138 input rows: 12 groups of 11 + 6

    // prologue: group 0 staged, group 1 prefetched — all within-wave.
    load_group<11>(A, B, y_start, 0, c0, c1, lane, pa, pb, pa2, pb2);
    write_group<11>(lds[w][0], lane, pa, pb, pa2, pb2);
    load_group<11>(A, B, y_start, 11, c0, c1, lane, pa, pb, pa2, pb2);
    process_group<11, true>(lds[w][0], lane, W2, vAB, vSX, loss_sum);

    // main loop: NO barriers. write(g) -> load(g+1) -> process(g).
    // DS in-order per wave makes write->read safe; the buffer parity keeps
    // process(g) reads separate from write(g+1) of the next iteration.
#pragma unroll 1
    for (int g = 1; g <= 11; ++g) {
        f2 (*cur)[LDS_S2] = lds[w][g & 1];
        write_group<11>(cur, lane, pa, pb, pa2, pb2);   // prefetched group g
        if (g <= 10)
            load_group<11>(A, B, y_start, (g + 1) * 11, c0, c1, lane,
                           pa, pb, pa2, pb2);
        else
            load_group<6>(A, B, y_start, 132, c0, c1, lane,
                          pa, pb, pa2, pb2);
        process_group<11, false>(cur, lane, W2, vAB, vSX, loss_sum);
    }

    // tail: group 12, rows 132..137 (132 % 11 == 0)
    write_group<6>(lds[w][0], lane, pa, pb, pa2, pb2);
    process_group<6, false>(lds[w][0], lane, W2, vAB, vSX, loss_sum);

    // ---- reduction: wave shuffle -> LDS across 4 waves -> atomicAdd ----
#pragma unroll
    for (int off = 32; off > 0; off >>= 1)
        loss_sum += __shfl_down(loss_sum, off, 64);
    if (lane == 0) red[w] = loss_sum;
    __syncthreads();   // the only barrier: final 4-wave reduction
    if (tid == 0) {
        const float s = red[0] + red[1] + red[2] + red[3];
        atomicAdd(out, s * (1.0f / ((float)N_IMG * H_IMG * W_IMG)));
    }
}

extern "C" void kernel_launch(void* const* d_in, const int* in_sizes, int n_in,
                              void* d_out, int out_size, void* d_ws, size_t ws_size,
                              hipStream_t stream) {
    const float* inp = (const float*)d_in[0];
    const float* tgt = (const float*)d_in[1];
    float* out = (float*)d_out;

    // d_out is poisoned 0xAA before every launch; zero it for the atomic sum.
    hipMemsetAsync(out, 0, sizeof(float), stream);

    const int grid = N_IMG * 4 * (H_IMG / TILE_H);  // 512 blocks x 4 waves
    ssim_main<<<grid, 256, 0, stream>>>(inp, tgt, out);
}